// Round 2
// baseline (568.968 us; speedup 1.0000x reference)
//
#include <hip/hip_runtime.h>

// SparseLinear: out[32,65536] = x[32,1024] @ (w * mask)[1024,65536] + b, fp32.
// Memory-bound floor: stream w+mask once = 512 MB -> ~82 us @ 6.3 TB/s.
//
// R2 post-mortem: the 2x 1-GiB fillBuffer dispatches (~322 us/iter) are the
// harness re-poisoning the WORKSPACE *unconditionally* (they persisted with
// zero ws use). So ws is free to use, and 322 us is an untouchable floor.
// Accounting: 504 = 322 (fills) + 4 (init) + ~178 (sl_partial + atomics).
//
// R3 (this round): sl_partial is LDS-broadcast-bound, not HBM-bound:
// 2048 wave-uniform ds_read_b128 per wave x 16 waves/CU x ~12 cyc = 164 us
// (matches observed ~160). HBM floor is 81 us, VALU 27 us. Fix: move the
// x broadcast off the LDS pipe onto the SCALAR pipe — stage xT[1024][32]
// in the free workspace, read it at wave-uniform addresses through a
// const __restrict__ pointer so LLVM emits merged s_load_dwordx8/16, and
// v_fmac takes the SGPR operand directly. LDS + barrier deleted entirely.

#define IN_DIM 1024
#define OUT_DIM 65536
#define BATCH 32
#define KSPLIT 4
#define KCHUNK (IN_DIM / KSPLIT)   // 256
#define BLOCK 256
#define U 8
#define NG (KCHUNK / U)            // 32 groups per chunk

// ---------- main kernel: x via scalar (uniform) loads from transposed xT ----
__global__ __launch_bounds__(BLOCK, 4) void sl_partial_s(
    const float* __restrict__ xT,   // [IN_DIM][BATCH], staged in ws
    const float* __restrict__ mask,
    const float* __restrict__ w, float* __restrict__ dst) {
  const int tid = threadIdx.x;
  const int j = blockIdx.x * BLOCK + tid;
  const int kc = blockIdx.y;
  const int k0 = kc * KCHUNK;

  float acc[BATCH];
#pragma unroll
  for (int i = 0; i < BATCH; ++i) acc[i] = 0.0f;

  const float* wp = w + (size_t)k0 * OUT_DIM + j;
  const float* mp = mask + (size_t)k0 * OUT_DIM + j;
  const float* xc = xT + (size_t)k0 * BATCH;  // block-uniform

  float wA[U], mA[U], wB[U], mB[U];

  auto loadg = [&](int g, float* wv, float* mv) {
#pragma unroll
    for (int u = 0; u < U; ++u) {
      size_t off = (size_t)(g * U + u) * OUT_DIM;
      wv[u] = __builtin_nontemporal_load(wp + off);  // streaming, no reuse
      mv[u] = __builtin_nontemporal_load(mp + off);
    }
  };
  auto computeg = [&](int g, const float* wv, const float* mv) {
#pragma unroll
    for (int u = 0; u < U; ++u) {
      float wm = wv[u] * mv[u];
      // Wave-uniform address -> scalar loads (SGPR); v_fmac with SGPR src.
      const float* xr = xc + (g * U + u) * BATCH;
#pragma unroll
      for (int i = 0; i < BATCH; ++i) acc[i] = fmaf(xr[i], wm, acc[i]);
    }
  };

  // Depth-1 software pipeline: 16 dword loads (4 KB/wave) in flight.
  loadg(0, wA, mA);
#pragma unroll 1
  for (int g = 0; g < NG; g += 2) {
    loadg(g + 1, wB, mB);  // g+1 <= NG-1 always (NG even)
    computeg(g, wA, mA);
    if (g + 2 < NG) loadg(g + 2, wA, mA);
    computeg(g + 1, wB, mB);
  }

  // Accumulate into out (pre-initialized to b). Coalesced L2 RMW, 4-way
  // same-address contention across kc chunks (~18 us tail).
#pragma unroll
  for (int i = 0; i < BATCH; ++i)
    atomicAdd(dst + (size_t)i * OUT_DIM + j, acc[i]);
}

// ---------- fallback main kernel (no ws): LDS broadcast, R2 version --------
__global__ __launch_bounds__(BLOCK, 4) void sl_partial_lds(
    const float* __restrict__ x, const float* __restrict__ mask,
    const float* __restrict__ w, float* __restrict__ dst) {
  __shared__ float xT[KCHUNK * BATCH];  // 32 KB
  const int tid = threadIdx.x;
  const int j = blockIdx.x * BLOCK + tid;
  const int kc = blockIdx.y;
  const int k0 = kc * KCHUNK;

#pragma unroll
  for (int it = 0; it < (KCHUNK * BATCH) / BLOCK; ++it) {
    int idx = it * BLOCK + tid;
    int kl = idx & (KCHUNK - 1);
    int i = idx >> 8;  // KCHUNK == 256
    xT[kl * BATCH + i] = x[i * IN_DIM + k0 + kl];
  }
  __syncthreads();

  float acc[BATCH];
#pragma unroll
  for (int i = 0; i < BATCH; ++i) acc[i] = 0.0f;

  const float* wp = w + (size_t)k0 * OUT_DIM + j;
  const float* mp = mask + (size_t)k0 * OUT_DIM + j;

  float wA[U], mA[U], wB[U], mB[U];

  auto loadg = [&](int g, float* wv, float* mv) {
#pragma unroll
    for (int u = 0; u < U; ++u) {
      size_t off = (size_t)(g * U + u) * OUT_DIM;
      wv[u] = __builtin_nontemporal_load(wp + off);
      mv[u] = __builtin_nontemporal_load(mp + off);
    }
  };
  auto computeg = [&](int g, const float* wv, const float* mv) {
#pragma unroll
    for (int u = 0; u < U; ++u) {
      float wm = wv[u] * mv[u];
      const float4* xp = (const float4*)&xT[(g * U + u) * BATCH];
#pragma unroll
      for (int i4 = 0; i4 < BATCH / 4; ++i4) {
        float4 q = xp[i4];
        acc[i4 * 4 + 0] = fmaf(q.x, wm, acc[i4 * 4 + 0]);
        acc[i4 * 4 + 1] = fmaf(q.y, wm, acc[i4 * 4 + 1]);
        acc[i4 * 4 + 2] = fmaf(q.z, wm, acc[i4 * 4 + 2]);
        acc[i4 * 4 + 3] = fmaf(q.w, wm, acc[i4 * 4 + 3]);
      }
    }
  };

  loadg(0, wA, mA);
#pragma unroll 1
  for (int g = 0; g < NG; g += 2) {
    loadg(g + 1, wB, mB);
    computeg(g, wA, mA);
    if (g + 2 < NG) loadg(g + 2, wA, mA);
    computeg(g + 1, wB, mB);
  }

#pragma unroll
  for (int i = 0; i < BATCH; ++i)
    atomicAdd(dst + (size_t)i * OUT_DIM + j, acc[i]);
}

// ---------- init: out = b, plus transpose x -> xT in ws (if ws available) --
__global__ __launch_bounds__(BLOCK) void sl_init(
    const float* __restrict__ x, const float* __restrict__ b,
    float* __restrict__ out, float* __restrict__ xT) {
  const int g = blockIdx.x * BLOCK + threadIdx.x;  // 0..16383
  const float4 bv = ((const float4*)b)[g];
#pragma unroll
  for (int i = 0; i < BATCH; ++i)
    ((float4*)out)[(size_t)i * (OUT_DIM / 4) + g] = bv;

  if (xT != nullptr) {
    // 32768 elements, 2 per thread; reads coalesced (e = i*IN_DIM + k).
#pragma unroll
    for (int r = 0; r < 2; ++r) {
      int e = r * 16384 + g;
      int i = e >> 10;           // / IN_DIM
      int k = e & (IN_DIM - 1);
      xT[(size_t)k * BATCH + i] = x[e];
    }
  }
}

extern "C" void kernel_launch(void* const* d_in, const int* in_sizes, int n_in,
                              void* d_out, int out_size, void* d_ws, size_t ws_size,
                              hipStream_t stream) {
  const float* x = (const float*)d_in[0];
  const float* mask = (const float*)d_in[1];
  const float* w = (const float*)d_in[2];
  const float* b = (const float*)d_in[3];
  float* out = (float*)d_out;

  const size_t needXT = (size_t)IN_DIM * BATCH * sizeof(float);  // 128 KB
  if (ws_size >= needXT) {
    float* xT = (float*)d_ws;  // ws is re-poisoned unconditionally: free.
    hipLaunchKernelGGL(sl_init, dim3(OUT_DIM / 4 / BLOCK), dim3(BLOCK), 0,
                       stream, x, b, out, xT);
    hipLaunchKernelGGL(sl_partial_s, dim3(OUT_DIM / BLOCK, KSPLIT),
                       dim3(BLOCK), 0, stream, xT, mask, w, out);
  } else {
    hipLaunchKernelGGL(sl_init, dim3(OUT_DIM / 4 / BLOCK), dim3(BLOCK), 0,
                       stream, x, b, out, (float*)nullptr);
    hipLaunchKernelGGL(sl_partial_lds, dim3(OUT_DIM / BLOCK, KSPLIT),
                       dim3(BLOCK), 0, stream, x, mask, w, out);
  }
}

// Round 4
// 517.242 us; speedup vs baseline: 1.1000x; 1.1000x over previous
//
#include <hip/hip_runtime.h>

// SparseLinear: out[32,65536] = x[32,1024] @ (w * mask)[1024,65536] + b, fp32.
//
// Harness facts (R2/R3): 2x 1-GiB ws-poison fills (~322 us/iter) run
// UNCONDITIONALLY — untouchable floor. LLC retains ~250 MB of w+mask across
// iterations (FETCH=263 MB < 512 MB), so the streaming floor is < 82 us.
//
// R3 post-mortem: scalar-broadcast (s_load) path REGRESSED: VALUBusy 60%
// (~106 us issue vs 27 us FMA floor) — compiler-added VALU/wait overhead.
// Root problem is structural: 8 broadcast reads per k-step per wave is the
// same order as the FMA count, whatever pipe serves it.
//
// R4: amortize the broadcast with J-blocking. Each thread owns JT=4 column
// slices (j, j+256, j+512, j+768 — lane-contiguous per slice so w/mask loads
// AND the atomic tail stay coalesced; thread-local float4 columns would make
// component atomics stride-16 = 64 L2 sectors/instr). One x-broadcast
// (8 uniform ds_read_b128) now feeds 4x the FMAs.
// Per-CU model @ KSPLIT=8 (8 waves/CU): LDS 8192 ds x 12cy = 41 us,
// VALU 28 us, HBM <= 85 us -> memory-bound. Predict sl_partial ~90-115 us.
//
// R5: unchanged resubmit — R4 bench died on container infra (failed twice),
// kernel never executed. Measure before mutating.

#define IN_DIM 1024
#define OUT_DIM 65536
#define BATCH 32
#define KSPLIT 8
#define KCHUNK (IN_DIM / KSPLIT)   // 128
#define BLOCK 256
#define JT 4                       // column slices per thread, stride BLOCK
#define U 2                        // k-steps per load group
#define NG (KCHUNK / U)            // 64 groups

__global__ __launch_bounds__(BLOCK, 2) void sl_partial_j4(
    const float* __restrict__ x, const float* __restrict__ mask,
    const float* __restrict__ w, float* __restrict__ dst) {
  __shared__ float xT[KCHUNK * BATCH];  // 16 KB: xT[kl*32+i] = x[i][k0+kl]
  const int tid = threadIdx.x;
  const int jb = blockIdx.x * (BLOCK * JT) + tid;  // slice s at jb + s*BLOCK
  const int kc = blockIdx.y;
  const int k0 = kc * KCHUNK;

  // One-time x stage (coalesced global reads; LDS write conflict is
  // one-time, ~1 us/block, acceptable).
#pragma unroll
  for (int it = 0; it < (KCHUNK * BATCH) / BLOCK; ++it) {
    int idx = it * BLOCK + tid;
    int kl = idx & (KCHUNK - 1);
    int i = idx >> 7;  // KCHUNK == 128
    xT[kl * BATCH + i] = x[i * IN_DIM + k0 + kl];
  }
  __syncthreads();  // only barrier in the kernel

  float acc[JT][BATCH];  // 128 VGPRs
#pragma unroll
  for (int s = 0; s < JT; ++s)
#pragma unroll
    for (int i = 0; i < BATCH; ++i) acc[s][i] = 0.0f;

  const float* wp = w + (size_t)k0 * OUT_DIM + jb;
  const float* mp = mask + (size_t)k0 * OUT_DIM + jb;

  // Per group: U k-steps x JT slices of (w, mask) = 16 dwords.
  float wA[U][JT], mA[U][JT], wB[U][JT], mB[U][JT];

  auto loadg = [&](int g, float (*wv)[JT], float (*mv)[JT]) {
#pragma unroll
    for (int u = 0; u < U; ++u) {
      const float* wk = wp + (size_t)(g * U + u) * OUT_DIM;
      const float* mk = mp + (size_t)(g * U + u) * OUT_DIM;
#pragma unroll
      for (int s = 0; s < JT; ++s) {
        // s*BLOCK*4 = 0/1024/2048/3072 B -> folds into the 13-bit imm offset.
        wv[u][s] = __builtin_nontemporal_load(wk + s * BLOCK);
        mv[u][s] = __builtin_nontemporal_load(mk + s * BLOCK);
      }
    }
  };
  auto computeg = [&](int g, float (*wv)[JT], float (*mv)[JT]) {
#pragma unroll
    for (int u = 0; u < U; ++u) {
      float wm[JT];
#pragma unroll
      for (int s = 0; s < JT; ++s) wm[s] = wv[u][s] * mv[u][s];
      const float4* xp = (const float4*)&xT[(g * U + u) * BATCH];
#pragma unroll
      for (int i4 = 0; i4 < BATCH / 4; ++i4) {
        float4 q = xp[i4];  // wave-uniform -> LDS broadcast, 1 read / 16 FMA
#pragma unroll
        for (int s = 0; s < JT; ++s) {
          acc[s][i4 * 4 + 0] = fmaf(q.x, wm[s], acc[s][i4 * 4 + 0]);
          acc[s][i4 * 4 + 1] = fmaf(q.y, wm[s], acc[s][i4 * 4 + 1]);
          acc[s][i4 * 4 + 2] = fmaf(q.z, wm[s], acc[s][i4 * 4 + 2]);
          acc[s][i4 * 4 + 3] = fmaf(q.w, wm[s], acc[s][i4 * 4 + 3]);
        }
      }
    }
  };

  // Depth-1 software pipeline: up to 32 dword loads (8 KB/wave) in flight.
  loadg(0, wA, mA);
#pragma unroll 1
  for (int g = 0; g < NG; g += 2) {
    loadg(g + 1, wB, mB);  // g+1 <= NG-1 always (NG even)
    computeg(g, wA, mA);
    if (g + 2 < NG) loadg(g + 2, wA, mA);
    computeg(g + 1, wB, mB);
  }

  // Atomic tail into out (pre-initialized to b). Per slice the 64 lanes are
  // 4B-contiguous -> 4 L2 sectors per wave-instr, ~14 us total, overlapped.
#pragma unroll
  for (int s = 0; s < JT; ++s)
#pragma unroll
    for (int i = 0; i < BATCH; ++i)
      atomicAdd(dst + (size_t)i * OUT_DIM + jb + s * BLOCK, acc[s][i]);
}

// out[i][j] = b[j]  (atomic accumulation base)
__global__ __launch_bounds__(BLOCK) void sl_init(
    const float* __restrict__ b, float* __restrict__ out) {
  const int j4 = blockIdx.x * BLOCK + threadIdx.x;
  const float4 bv = ((const float4*)b)[j4];
#pragma unroll
  for (int i = 0; i < BATCH; ++i)
    ((float4*)out)[(size_t)i * (OUT_DIM / 4) + j4] = bv;
}

extern "C" void kernel_launch(void* const* d_in, const int* in_sizes, int n_in,
                              void* d_out, int out_size, void* d_ws, size_t ws_size,
                              hipStream_t stream) {
  const float* x = (const float*)d_in[0];
  const float* mask = (const float*)d_in[1];
  const float* w = (const float*)d_in[2];
  const float* b = (const float*)d_in[3];
  float* out = (float*)d_out;
  (void)d_ws;
  (void)ws_size;  // ws poison is unconditional; not using it costs nothing

  hipLaunchKernelGGL(sl_init, dim3(OUT_DIM / 4 / BLOCK), dim3(BLOCK), 0,
                     stream, b, out);
  hipLaunchKernelGGL(sl_partial_j4, dim3(OUT_DIM / (BLOCK * JT), KSPLIT),
                     dim3(BLOCK), 0, stream, x, mask, w, out);
}

// Round 6
// 517.231 us; speedup vs baseline: 1.1000x; 1.0000x over previous
//
#include <hip/hip_runtime.h>

// SparseLinear: out[32,65536] = x[32,1024] @ (w * mask)[1024,65536] + b, fp32.
//
// Harness facts: 2x 1-GiB ws-poison fills (~322 us/iter) run UNCONDITIONALLY
// — untouchable floor, and ws use is therefore FREE. LLC retains ~250 MB of
// w+mask across iterations (FETCH=263 MB < 512 MB).
//
// R4 post-mortem (517 us total): atomic tail with KSPLIT=8 = 16.8M lane
// atomics, 8-way same-address contention (~67 MB serialized RMW), and the
// stride-BLOCK slice layout (needed only for atomic coalescing) costs 8
// dword VMEM instrs per k-step instead of 2 dwordx4.
//
// R5/R6: drop atomics, use the free ws. Thread owns 4 CONTIGUOUS columns
// (one float4): w/mask loads are dwordx4 (1 KB/wave-instr, 4x fewer VMEM
// instrs), partials stored plain (LLC-resident for reduce), reduce adds b.
// Per-CU model @ KSPLIT=8 (8 waves/CU, 2/SIMD): LDS broadcast 8192 ds_read
// x 12 cyc = 41 us (invariant), VALU 28 us, HBM ~55-80 us -> memory-bound.
// Predict partial 75-100 us, reduce ~13 us, total ~440.
//
// R6 fix: __builtin_nontemporal_load rejects HIP_vector_type<float,4>*
// (struct). Use clang ext_vector_type(4) float — accepted by the builtin,
// still lowers to global_load_dwordx4.

#define IN_DIM 1024
#define OUT_DIM 65536
#define BATCH 32
#define KSPLIT 8
#define KCHUNK (IN_DIM / KSPLIT)   // 128
#define BLOCK 256
#define U 2                        // k-steps per load group
#define NG (KCHUNK / U)            // 64 groups
#define OUT4 (OUT_DIM / 4)         // 16384 float4 columns

typedef float f4 __attribute__((ext_vector_type(4)));

template <bool ATOMIC>
__global__ __launch_bounds__(BLOCK, 2) void sl_partial_v4(
    const float* __restrict__ x, const float* __restrict__ mask,
    const float* __restrict__ w, float* __restrict__ dst) {
  __shared__ float xT[KCHUNK * BATCH];  // 16 KB: xT[kl*32+i] = x[i][k0+kl]
  const int tid = threadIdx.x;
  const int j4 = blockIdx.x * BLOCK + tid;  // this thread's float4 column
  const int kc = blockIdx.y;
  const int k0 = kc * KCHUNK;

  // One-time x stage. Coalesced global reads; the LDS write bank conflict
  // here is one-time (~1K cyc/wave), negligible.
#pragma unroll
  for (int it = 0; it < (KCHUNK * BATCH) / BLOCK; ++it) {
    int idx = it * BLOCK + tid;
    int kl = idx & (KCHUNK - 1);
    int i = idx >> 7;  // KCHUNK == 128
    xT[kl * BATCH + i] = x[i * IN_DIM + k0 + kl];
  }
  __syncthreads();  // only barrier in the kernel

  f4 acc[BATCH];  // 128 VGPRs: acc[i] = out[i][j4*4 .. j4*4+3]
#pragma unroll
  for (int i = 0; i < BATCH; ++i) acc[i] = (f4)(0.0f);

  const f4* wp = (const f4*)w + (size_t)k0 * OUT4 + j4;
  const f4* mp = (const f4*)mask + (size_t)k0 * OUT4 + j4;

  f4 wA[U], mA[U], wB[U], mB[U];

  auto loadg = [&](int g, f4* wv, f4* mv) {
#pragma unroll
    for (int u = 0; u < U; ++u) {
      size_t off = (size_t)(g * U + u) * OUT4;
      wv[u] = __builtin_nontemporal_load(wp + off);  // dwordx4, streaming
      mv[u] = __builtin_nontemporal_load(mp + off);
    }
  };
  auto computeg = [&](int g, const f4* wv, const f4* mv) {
#pragma unroll
    for (int u = 0; u < U; ++u) {
      f4 wm = wv[u] * mv[u];
      const f4* xp = (const f4*)&xT[(g * U + u) * BATCH];
#pragma unroll
      for (int i4 = 0; i4 < BATCH / 4; ++i4) {
        f4 q = xp[i4];  // wave-uniform -> LDS broadcast, 1 read / 16 FMA
        acc[i4 * 4 + 0].x = fmaf(q.x, wm.x, acc[i4 * 4 + 0].x);
        acc[i4 * 4 + 0].y = fmaf(q.x, wm.y, acc[i4 * 4 + 0].y);
        acc[i4 * 4 + 0].z = fmaf(q.x, wm.z, acc[i4 * 4 + 0].z);
        acc[i4 * 4 + 0].w = fmaf(q.x, wm.w, acc[i4 * 4 + 0].w);
        acc[i4 * 4 + 1].x = fmaf(q.y, wm.x, acc[i4 * 4 + 1].x);
        acc[i4 * 4 + 1].y = fmaf(q.y, wm.y, acc[i4 * 4 + 1].y);
        acc[i4 * 4 + 1].z = fmaf(q.y, wm.z, acc[i4 * 4 + 1].z);
        acc[i4 * 4 + 1].w = fmaf(q.y, wm.w, acc[i4 * 4 + 1].w);
        acc[i4 * 4 + 2].x = fmaf(q.z, wm.x, acc[i4 * 4 + 2].x);
        acc[i4 * 4 + 2].y = fmaf(q.z, wm.y, acc[i4 * 4 + 2].y);
        acc[i4 * 4 + 2].z = fmaf(q.z, wm.z, acc[i4 * 4 + 2].z);
        acc[i4 * 4 + 2].w = fmaf(q.z, wm.w, acc[i4 * 4 + 2].w);
        acc[i4 * 4 + 3].x = fmaf(q.w, wm.x, acc[i4 * 4 + 3].x);
        acc[i4 * 4 + 3].y = fmaf(q.w, wm.y, acc[i4 * 4 + 3].y);
        acc[i4 * 4 + 3].z = fmaf(q.w, wm.z, acc[i4 * 4 + 3].z);
        acc[i4 * 4 + 3].w = fmaf(q.w, wm.w, acc[i4 * 4 + 3].w);
      }
    }
  };

  // Depth-1 software pipeline: 8 dwordx4 loads (8 KB/wave) in flight.
  loadg(0, wA, mA);
#pragma unroll 1
  for (int g = 0; g < NG; g += 2) {
    loadg(g + 1, wB, mB);  // g+1 <= NG-1 always (NG even)
    computeg(g, wA, mA);
    if (g + 2 < NG) loadg(g + 2, wA, mA);
    computeg(g + 1, wB, mB);
  }

  if (ATOMIC) {
    // Fallback only (ws too small): per-component atomics, stride-16B lanes.
#pragma unroll
    for (int i = 0; i < BATCH; ++i) {
      float* d = dst + (size_t)i * OUT_DIM + j4 * 4;
      atomicAdd(d + 0, acc[i].x);
      atomicAdd(d + 1, acc[i].y);
      atomicAdd(d + 2, acc[i].z);
      atomicAdd(d + 3, acc[i].w);
    }
  } else {
    // Partial store to ws[kc][i][j4]: dwordx4, lane-contiguous (1 KB/instr).
    // Plain (temporal) stores so the reduce pass hits them in LLC.
    f4* wsp = (f4*)dst;
#pragma unroll
    for (int i = 0; i < BATCH; ++i)
      wsp[(size_t)(kc * BATCH + i) * OUT4 + j4] = acc[i];
  }
}

// out[i][j] = b[j] + sum_kc partial[kc][i][j]
__global__ __launch_bounds__(BLOCK) void sl_reduce(
    const float* __restrict__ ws, const float* __restrict__ b,
    float* __restrict__ out) {
  const int j4 = blockIdx.x * BLOCK + threadIdx.x;
  const int i = blockIdx.y;
  f4 s = ((const f4*)b)[j4];
#pragma unroll
  for (int kc = 0; kc < KSPLIT; ++kc) {
    f4 p = ((const f4*)ws)[(size_t)(kc * BATCH + i) * OUT4 + j4];
    s += p;
  }
  ((f4*)out)[(size_t)i * OUT4 + j4] = s;
}

// Atomic-fallback init: out[i][j] = b[j]
__global__ __launch_bounds__(BLOCK) void sl_init(
    const float* __restrict__ b, float* __restrict__ out) {
  const int j4 = blockIdx.x * BLOCK + threadIdx.x;
  const f4 bv = ((const f4*)b)[j4];
#pragma unroll
  for (int i = 0; i < BATCH; ++i)
    ((f4*)out)[(size_t)i * OUT4 + j4] = bv;
}

extern "C" void kernel_launch(void* const* d_in, const int* in_sizes, int n_in,
                              void* d_out, int out_size, void* d_ws, size_t ws_size,
                              hipStream_t stream) {
  const float* x = (const float*)d_in[0];
  const float* mask = (const float*)d_in[1];
  const float* w = (const float*)d_in[2];
  const float* b = (const float*)d_in[3];
  float* out = (float*)d_out;

  const size_t need = (size_t)KSPLIT * BATCH * OUT_DIM * sizeof(float);  // 64 MB
  if (ws_size >= need) {
    hipLaunchKernelGGL((sl_partial_v4<false>), dim3(OUT4 / BLOCK, KSPLIT),
                       dim3(BLOCK), 0, stream, x, mask, w, (float*)d_ws);
    hipLaunchKernelGGL(sl_reduce, dim3(OUT4 / BLOCK, BATCH), dim3(BLOCK), 0,
                       stream, (const float*)d_ws, b, out);
  } else {
    hipLaunchKernelGGL(sl_init, dim3(OUT4 / BLOCK), dim3(BLOCK), 0, stream, b,
                       out);
    hipLaunchKernelGGL((sl_partial_v4<true>), dim3(OUT4 / BLOCK, KSPLIT),
                       dim3(BLOCK), 0, stream, x, mask, w, out);
  }
}